// Round 3
// baseline (436.040 us; speedup 1.0000x reference)
//
#include <hip/hip_runtime.h>

typedef short short8 __attribute__((ext_vector_type(8)));
typedef short short4v __attribute__((ext_vector_type(4)));
typedef float f32x4 __attribute__((ext_vector_type(4)));

__device__ __forceinline__ float bf2f(unsigned short u) {
  union { unsigned int i; float f; } v; v.i = ((unsigned int)u) << 16; return v.f;
}
__device__ __forceinline__ unsigned short f2bf(float f) {
  unsigned int x = __float_as_uint(f);
  unsigned int r = (x + 0x7fffu + ((x >> 16) & 1u)) >> 16;  // RNE
  return (unsigned short)r;
}

typedef __attribute__((address_space(1))) void* gas_t;
typedef __attribute__((address_space(3))) void* las_t;
__device__ __forceinline__ void async16(const float* g, float* l) {
  __builtin_amdgcn_global_load_lds((gas_t)g, (las_t)l, 16, 0, 0);
}

// ---------------------------------------------------------------------------
// K0: build combined matrices in MFMA B-fragment layout (bf16).
//   A[k=p][n=g*64+d]    = 0.25 * sum_c Wq[p][16g+c] * Wk[d][16g+c]
//   WVO[k=g*64+d][n=q'] =        sum_c Wv[d][16g+c] * Wout[16g+c][q']
// frag layout: elem(k,n) -> (k>>5)*8192 + n*32 + (k&31)
// ---------------------------------------------------------------------------
__global__ __launch_bounds__(256) void prep_kernel(
    const float* __restrict__ Wq, const float* __restrict__ Wk,
    const float* __restrict__ Wv, const float* __restrict__ Wout,
    unsigned short* __restrict__ Afrag, unsigned short* __restrict__ WVOfrag) {
  const int b = blockIdx.x, tid = threadIdx.x;
  if (b < 256) {
    const int p = b, g = tid >> 6, d = tid & 63;
    float s = 0.f;
#pragma unroll
    for (int c = 0; c < 16; ++c)
      s += Wq[p * 64 + g * 16 + c] * Wk[d * 64 + g * 16 + c];
    s *= 0.25f;  // 1/sqrt(PPG) folded into scores
    const int n = g * 64 + d, k = p;
    Afrag[(size_t)(k >> 5) * 8192 + n * 32 + (k & 31)] = f2bf(s);
  } else {
    const int row = b - 256, g = row >> 6, d = row & 63, q = tid;
    float s = 0.f;
#pragma unroll
    for (int c = 0; c < 16; ++c)
      s += Wv[d * 64 + g * 16 + c] * Wout[(g * 16 + c) * 256 + q];
    WVOfrag[(size_t)(row >> 5) * 8192 + q * 32 + (row & 31)] = f2bf(s);
  }
}

// ---------------------------------------------------------------------------
// K1/K3: C[16384,256] = X[16384,256] @ W[256,256], bf16 MFMA 16x16x32.
// MODE 0: X fp32 (q), out bf16 (qk).  MODE 1: X bf16 (y), out fp32 + bias.
// 32 rows/WG, grid 512 -> 2 WGs/CU.
// ---------------------------------------------------------------------------
template <int MODE>
__global__ __launch_bounds__(256) void gemm256_kernel(
    const void* __restrict__ Xv, const unsigned short* __restrict__ Wfrag,
    void* __restrict__ Outv, const float* __restrict__ bias) {
  __shared__ unsigned short A_s[32 * 40];
  const int tid = threadIdx.x;
  const int m0 = blockIdx.x * 32;
  const int w = tid >> 6, lane = tid & 63;
  const int m_l = lane & 15, quad = lane >> 4;
  const int nt0 = (w & 1) * 8, m16 = (w >> 1) * 16;
  const int srow = tid >> 3, sc4 = (tid & 7) * 4;

  f32x4 acc[8];
#pragma unroll
  for (int i = 0; i < 8; ++i) acc[i] = (f32x4){0.f, 0.f, 0.f, 0.f};

  for (int ks = 0; ks < 8; ++ks) {
    if (MODE == 0) {
      const float* X = (const float*)Xv;
      float4 x = *(const float4*)(X + (size_t)(m0 + srow) * 256 + ks * 32 + sc4);
      short4v vv;
      vv[0] = (short)f2bf(x.x); vv[1] = (short)f2bf(x.y);
      vv[2] = (short)f2bf(x.z); vv[3] = (short)f2bf(x.w);
      *(short4v*)&A_s[srow * 40 + sc4] = vv;
    } else {
      const unsigned short* X = (const unsigned short*)Xv;
      uint2 xv = *(const uint2*)(X + (size_t)(m0 + srow) * 256 + ks * 32 + sc4);
      *(uint2*)&A_s[srow * 40 + sc4] = xv;
    }
    __syncthreads();
    short8 a = *(const short8*)&A_s[(m16 + m_l) * 40 + quad * 8];
#pragma unroll
    for (int j = 0; j < 8; ++j) {
      const unsigned short* bp =
          Wfrag + ((size_t)ks * 256 + (nt0 + j) * 16 + m_l) * 32 + quad * 8;
      short8 bfr = *(const short8*)bp;
      acc[j] = __builtin_amdgcn_mfma_f32_16x16x32_bf16(a, bfr, acc[j], 0, 0, 0);
    }
    __syncthreads();
  }
  const int row0 = m0 + m16 + quad * 4;  // C/D: col=lane&15, row=quad*4+reg
#pragma unroll
  for (int j = 0; j < 8; ++j) {
    const int col = (nt0 + j) * 16 + m_l;
    if (MODE == 0) {
      unsigned short* Out = (unsigned short*)Outv;
#pragma unroll
      for (int r = 0; r < 4; ++r)
        Out[(size_t)(row0 + r) * 256 + col] = f2bf(acc[j][r]);
    } else {
      float* Out = (float*)Outv;
      const float bb = bias[col];
#pragma unroll
      for (int r = 0; r < 4; ++r)
        Out[(size_t)(row0 + r) * 256 + col] = acc[j][r] + bb;
    }
  }
}

// ---------------------------------------------------------------------------
// K2: streaming attention. WG = (n,i): 64 pixels x 4 groups, one thread per
// (j,g). Streams t=0..63; each step reads kv[n,t,i,:,:] = 16 KB CONTIGUOUS
// via global_load_lds into a 3-deep LDS ring. Per-thread softmax (no
// max-shift: scores bounded, sigma~0.33), y accumulated in 64 VGPRs.
// Chunk rotation (c+j)&15 keeps LDS reads at 2-way conflicts.
// ---------------------------------------------------------------------------
__global__ __launch_bounds__(256, 1) void attn_kernel(
    const float* __restrict__ kv, const unsigned short* __restrict__ qk,
    unsigned short* __restrict__ yout) {
  __shared__ float kvbuf[3][4096];        // 48 KB ring
  __shared__ unsigned short qk_s[16384];  // 32 KB (reused for y staging)

  const int tid = threadIdx.x;
  const int wgid = blockIdx.x;  // n*64 + i
  const int n = wgid >> 6, i = wgid & 63;
  const int j = tid >> 2, g = tid & 3;
  const int w = tid >> 6, lane = tid & 63;

  const float* kvblk = kv + ((size_t)n << 24) + ((size_t)i << 12);
  const int loff = w * 1024 + lane * 4;  // float offset in 4096-block

  // prologue: issue t=0 -> buf0, t=1 -> buf1
#pragma unroll
  for (int q = 0; q < 4; ++q)
    async16(kvblk + loff + q * 256, &kvbuf[0][loff + q * 256]);
#pragma unroll
  for (int q = 0; q < 4; ++q)
    async16(kvblk + (1 << 18) + loff + q * 256, &kvbuf[1][loff + q * 256]);

  // stage qk slab (64 pixels x 256 bf16 = 32 KB contiguous)
  const unsigned short* qkb = qk + ((size_t)wgid << 14);
#pragma unroll
  for (int it = 0; it < 8; ++it)
    *(uint4*)&qk_s[(it * 256 + tid) * 8] =
        *(const uint4*)(qkb + (it * 256 + tid) * 8);
  __syncthreads();  // also drains t0/t1 async loads — prologue only

  float qf[64];
#pragma unroll
  for (int c = 0; c < 16; ++c) {
    const int rot = (c + j) & 15;
    uint2 u = *(const uint2*)&qk_s[j * 256 + g * 64 + rot * 4];
    qf[4 * c + 0] = bf2f((unsigned short)(u.x & 0xffffu));
    qf[4 * c + 1] = bf2f((unsigned short)(u.x >> 16));
    qf[4 * c + 2] = bf2f((unsigned short)(u.y & 0xffffu));
    qf[4 * c + 3] = bf2f((unsigned short)(u.y >> 16));
  }

  float yac[64];
#pragma unroll
  for (int c = 0; c < 64; ++c) yac[c] = 0.f;
  float lsum = 0.f;

  int b = 0, ib = 2;
  for (int t = 0; t < 64; ++t) {
    if (t >= 1) __syncthreads();  // drains load(t+1); protects ring reuse
    if (t + 2 < 64) {
      const float* src = kvblk + ((size_t)(t + 2) << 18) + loff;
      float* dst = &kvbuf[ib][loff];
#pragma unroll
      for (int q = 0; q < 4; ++q) async16(src + q * 256, dst + q * 256);
    }
    const float* row = &kvbuf[b][j * 64];
    float s = 0.f;
    float4 cv[16];
#pragma unroll
    for (int c = 0; c < 16; ++c) {
      const int rot = (c + j) & 15;
      cv[c] = *(const float4*)(row + rot * 4);
      s = fmaf(cv[c].x, qf[4 * c + 0], s);
      s = fmaf(cv[c].y, qf[4 * c + 1], s);
      s = fmaf(cv[c].z, qf[4 * c + 2], s);
      s = fmaf(cv[c].w, qf[4 * c + 3], s);
    }
    const float p = __expf(s);
    lsum += p;
#pragma unroll
    for (int c = 0; c < 16; ++c) {
      yac[4 * c + 0] = fmaf(p, cv[c].x, yac[4 * c + 0]);
      yac[4 * c + 1] = fmaf(p, cv[c].y, yac[4 * c + 1]);
      yac[4 * c + 2] = fmaf(p, cv[c].z, yac[4 * c + 2]);
      yac[4 * c + 3] = fmaf(p, cv[c].w, yac[4 * c + 3]);
    }
    b = (b == 2) ? 0 : b + 1;
    ib = (ib == 2) ? 0 : ib + 1;
  }

  // epilogue: y = yac/lsum -> bf16 -> LDS (rotated back) -> contiguous store
  const float inv = 1.f / lsum;
  unsigned int* yst = (unsigned int*)qk_s;
#pragma unroll
  for (int c = 0; c < 16; ++c) {
    const int rot = (c + j) & 15;
    uint2 pk;
    pk.x = (unsigned int)f2bf(yac[4 * c + 0] * inv) |
           ((unsigned int)f2bf(yac[4 * c + 1] * inv) << 16);
    pk.y = (unsigned int)f2bf(yac[4 * c + 2] * inv) |
           ((unsigned int)f2bf(yac[4 * c + 3] * inv) << 16);
    *(uint2*)&yst[j * 128 + g * 32 + rot * 2] = pk;
  }
  __syncthreads();
  unsigned short* yo = yout + ((size_t)wgid << 14);
  const uint4* srcv = (const uint4*)qk_s;
#pragma unroll
  for (int it = 0; it < 8; ++it)
    *(uint4*)(yo + (it * 256 + tid) * 8) = srcv[it * 256 + tid];
}

// ---------------------------------------------------------------------------
extern "C" void kernel_launch(void* const* d_in, const int* in_sizes, int n_in,
                              void* d_out, int out_size, void* d_ws,
                              size_t ws_size, hipStream_t stream) {
  const float* q    = (const float*)d_in[0];
  const float* kv   = (const float*)d_in[1];
  const float* Wq   = (const float*)d_in[2];
  const float* Wk   = (const float*)d_in[3];
  const float* Wv   = (const float*)d_in[4];
  const float* Wout = (const float*)d_in[5];
  const float* bout = (const float*)d_in[6];

  // workspace (ushort units): A frag 65536 | WVO frag 65536 | qk 4.19M | y 4.19M
  unsigned short* ws      = (unsigned short*)d_ws;
  unsigned short* Afrag   = ws;
  unsigned short* WVOfrag = ws + 65536;
  unsigned short* qk_ws   = ws + 131072;
  unsigned short* y_ws    = ws + 131072 + 4194304;

  hipLaunchKernelGGL(prep_kernel, dim3(512), dim3(256), 0, stream,
                     Wq, Wk, Wv, Wout, Afrag, WVOfrag);
  hipLaunchKernelGGL((gemm256_kernel<0>), dim3(512), dim3(256), 0, stream,
                     (const void*)q, Afrag, (void*)qk_ws, (const float*)nullptr);
  hipLaunchKernelGGL(attn_kernel, dim3(256), dim3(256), 0, stream,
                     kv, qk_ws, y_ws);
  hipLaunchKernelGGL((gemm256_kernel<1>), dim3(512), dim3(256), 0, stream,
                     (const void*)y_ws, WVOfrag, d_out, bout);
}

// Round 4
// 404.816 us; speedup vs baseline: 1.0771x; 1.0771x over previous
//
#include <hip/hip_runtime.h>

typedef short short8 __attribute__((ext_vector_type(8)));
typedef float f32x4 __attribute__((ext_vector_type(4)));

__device__ __forceinline__ float bf2f(unsigned short u) {
  union { unsigned int i; float f; } v; v.i = ((unsigned int)u) << 16; return v.f;
}
__device__ __forceinline__ unsigned short f2bf(float f) {
  unsigned int x = __float_as_uint(f);
  unsigned int r = (x + 0x7fffu + ((x >> 16) & 1u)) >> 16;  // RNE
  return (unsigned short)r;
}

typedef __attribute__((address_space(1))) void* gas_t;
typedef __attribute__((address_space(3))) void* las_t;
__device__ __forceinline__ void async16(const float* g, float* l) {
  __builtin_amdgcn_global_load_lds((gas_t)g, (las_t)l, 16, 0, 0);
}

// ---------------------------------------------------------------------------
// K0: build combined matrices in MFMA B-fragment layout (bf16).
//   A[k=p][n=g*64+d]    = 0.25 * sum_c Wq[p][16g+c] * Wk[d][16g+c]
//   WVO[k=g*64+d][n=q'] =        sum_c Wv[d][16g+c] * Wout[16g+c][q']
// frag layout: elem(k,n) -> (k>>5)*8192 + n*32 + (k&31)
// ---------------------------------------------------------------------------
__global__ __launch_bounds__(256) void prep_kernel(
    const float* __restrict__ Wq, const float* __restrict__ Wk,
    const float* __restrict__ Wv, const float* __restrict__ Wout,
    unsigned short* __restrict__ Afrag, unsigned short* __restrict__ WVOfrag) {
  const int b = blockIdx.x, tid = threadIdx.x;
  if (b < 256) {
    const int p = b, g = tid >> 6, d = tid & 63;
    float s = 0.f;
#pragma unroll
    for (int c = 0; c < 16; ++c)
      s += Wq[p * 64 + g * 16 + c] * Wk[d * 64 + g * 16 + c];
    s *= 0.25f;  // 1/sqrt(PPG) folded into scores
    const int n = g * 64 + d, k = p;
    Afrag[(size_t)(k >> 5) * 8192 + n * 32 + (k & 31)] = f2bf(s);
  } else {
    const int row = b - 256, g = row >> 6, d = row & 63, q = tid;
    float s = 0.f;
#pragma unroll
    for (int c = 0; c < 16; ++c)
      s += Wv[d * 64 + g * 16 + c] * Wout[(g * 16 + c) * 256 + q];
    WVOfrag[(size_t)(row >> 5) * 8192 + q * 32 + (row & 31)] = f2bf(s);
  }
}

// ---------------------------------------------------------------------------
// K1: fully fused. One WG per (n,i) row: 64 pixels. Phases:
//  A) qk = q_rows[64x256] @ Afrag  -> LDS (bf16), MFMA 16x16x32
//  B) stream kv[n,t,i,:,:] (16 KB contiguous/step) via global_load_lds into a
//     3-deep ring; per-thread softmax (no max-shift, scores bounded) and y
//     accumulation in VGPRs. Barrier order: [barrier; prefetch t+2; compute t]
//     so the barrier's vmcnt(0) only drains the load issued a full iter ago.
//  C) out = y[64x256] @ WVOfrag + bias -> global (fp32)
// ---------------------------------------------------------------------------
__global__ __launch_bounds__(256, 1) void fused_kernel(
    const float* __restrict__ q, const float* __restrict__ kv,
    const unsigned short* __restrict__ Afrag,
    const unsigned short* __restrict__ WVOfrag,
    const float* __restrict__ bias, float* __restrict__ Out) {
  __shared__ float kvbuf[3][4096];         // 48 KB ring
  __shared__ unsigned short qk_s[64 * 256];  // 32 KB: qk, then reused for y
  __shared__ unsigned short A_s[64 * 40];    // 5 KB staging for phase A

  const int tid = threadIdx.x;
  const int wgid = blockIdx.x;  // n*64 + i
  const int w = tid >> 6, lane = tid & 63;
  const int m_l = lane & 15, quad = lane >> 4;
  const int j = tid >> 2, g = tid & 3;  // phase-B mapping: thread = (pixel j, group g)

  // ---------------- Phase A: qk = q_rows @ A ------------------------------
  {
    const float* qrow = q + (size_t)wgid * 64 * 256;
    const int srow = tid >> 2, sc = (tid & 3) * 8;
    f32x4 acc[16];
#pragma unroll
    for (int i = 0; i < 16; ++i) acc[i] = (f32x4){0.f, 0.f, 0.f, 0.f};
    for (int ks = 0; ks < 8; ++ks) {
      const float4* xp = (const float4*)(qrow + (size_t)srow * 256 + ks * 32 + sc);
      float4 x0 = xp[0], x1 = xp[1];
      short8 vv;
      vv[0] = (short)f2bf(x0.x); vv[1] = (short)f2bf(x0.y);
      vv[2] = (short)f2bf(x0.z); vv[3] = (short)f2bf(x0.w);
      vv[4] = (short)f2bf(x1.x); vv[5] = (short)f2bf(x1.y);
      vv[6] = (short)f2bf(x1.z); vv[7] = (short)f2bf(x1.w);
      *(short8*)&A_s[srow * 40 + sc] = vv;
      __syncthreads();
      short8 a = *(const short8*)&A_s[(w * 16 + m_l) * 40 + quad * 8];
#pragma unroll
      for (int nt = 0; nt < 16; ++nt) {
        short8 bf = *(const short8*)(Afrag +
            ((size_t)ks * 256 + nt * 16 + m_l) * 32 + quad * 8);
        acc[nt] = __builtin_amdgcn_mfma_f32_16x16x32_bf16(a, bf, acc[nt], 0, 0, 0);
      }
      __syncthreads();
    }
    // C/D: col=lane&15, row=quad*4+r  -> qk_s[row][col] bf16
#pragma unroll
    for (int nt = 0; nt < 16; ++nt) {
      const int col = nt * 16 + m_l;
#pragma unroll
      for (int r = 0; r < 4; ++r)
        qk_s[(w * 16 + quad * 4 + r) * 256 + col] = f2bf(acc[nt][r]);
    }
  }

  // ---------------- Phase B: streaming attention --------------------------
  const float* kvblk =
      kv + ((size_t)(wgid >> 6) << 24) + ((size_t)(wgid & 63) << 12);
  const int loff = w * 1024 + lane * 4;  // float offset; lane*16 B per wave

#pragma unroll
  for (int qq = 0; qq < 4; ++qq)
    async16(kvblk + loff + qq * 256, &kvbuf[0][loff + qq * 256]);
#pragma unroll
  for (int qq = 0; qq < 4; ++qq)
    async16(kvblk + (1 << 18) + loff + qq * 256, &kvbuf[1][loff + qq * 256]);
  __syncthreads();  // qk_s visible to all + t0/t1 staged

  float qf[64];
#pragma unroll
  for (int c = 0; c < 16; ++c) {
    const int rot = (c + j) & 15;
    uint2 u = *(const uint2*)&qk_s[j * 256 + g * 64 + rot * 4];
    qf[4 * c + 0] = bf2f((unsigned short)(u.x & 0xffffu));
    qf[4 * c + 1] = bf2f((unsigned short)(u.x >> 16));
    qf[4 * c + 2] = bf2f((unsigned short)(u.y & 0xffffu));
    qf[4 * c + 3] = bf2f((unsigned short)(u.y >> 16));
  }

  float yac[64];
#pragma unroll
  for (int c = 0; c < 64; ++c) yac[c] = 0.f;
  float lsum = 0.f;

  int b = 0, ib = 2;
  for (int t = 0; t < 64; ++t) {
    if (t >= 1) __syncthreads();  // drains load(t+1) only; protects ring WAR
    if (t + 2 < 64) {
      const float* src = kvblk + ((size_t)(t + 2) << 18) + loff;
      float* dst = &kvbuf[ib][loff];
#pragma unroll
      for (int qq = 0; qq < 4; ++qq) async16(src + qq * 256, dst + qq * 256);
    }
    const float* row = &kvbuf[b][j * 64];
    float s = 0.f;
    float4 cv[16];
#pragma unroll
    for (int c = 0; c < 16; ++c) {
      const int rot = (c + j) & 15;
      cv[c] = *(const float4*)(row + rot * 4);
      s = fmaf(cv[c].x, qf[4 * c + 0], s);
      s = fmaf(cv[c].y, qf[4 * c + 1], s);
      s = fmaf(cv[c].z, qf[4 * c + 2], s);
      s = fmaf(cv[c].w, qf[4 * c + 3], s);
    }
    const float p = __expf(s);
    lsum += p;
#pragma unroll
    for (int c = 0; c < 16; ++c) {
      yac[4 * c + 0] = fmaf(p, cv[c].x, yac[4 * c + 0]);
      yac[4 * c + 1] = fmaf(p, cv[c].y, yac[4 * c + 1]);
      yac[4 * c + 2] = fmaf(p, cv[c].z, yac[4 * c + 2]);
      yac[4 * c + 3] = fmaf(p, cv[c].w, yac[4 * c + 3]);
    }
    b = (b == 2) ? 0 : b + 1;
    ib = (ib == 2) ? 0 : ib + 1;
  }

  // y -> qk_s (bf16, plain [j][gd] layout; rot maps chunks back)
  {
    const float inv = 1.f / lsum;
    unsigned int* yst = (unsigned int*)qk_s;
#pragma unroll
    for (int c = 0; c < 16; ++c) {
      const int rot = (c + j) & 15;
      uint2 pk;
      pk.x = (unsigned int)f2bf(yac[4 * c + 0] * inv) |
             ((unsigned int)f2bf(yac[4 * c + 1] * inv) << 16);
      pk.y = (unsigned int)f2bf(yac[4 * c + 2] * inv) |
             ((unsigned int)f2bf(yac[4 * c + 3] * inv) << 16);
      *(uint2*)&yst[j * 128 + g * 32 + rot * 2] = pk;
    }
  }
  __syncthreads();

  // ---------------- Phase C: out = y @ WVO + bias -------------------------
  {
    f32x4 acc[16];
#pragma unroll
    for (int i = 0; i < 16; ++i) acc[i] = (f32x4){0.f, 0.f, 0.f, 0.f};
    for (int ks = 0; ks < 8; ++ks) {
      // A-operand: A[m=lane&15][k=quad*8+i] from qk_s (y), row = w*16+m_l
      short8 a = *(const short8*)&qk_s[(w * 16 + m_l) * 256 + ks * 32 + quad * 8];
#pragma unroll
      for (int nt = 0; nt < 16; ++nt) {
        short8 bf = *(const short8*)(WVOfrag +
            ((size_t)ks * 256 + nt * 16 + m_l) * 32 + quad * 8);
        acc[nt] = __builtin_amdgcn_mfma_f32_16x16x32_bf16(a, bf, acc[nt], 0, 0, 0);
      }
    }
    float* outb = Out + (size_t)wgid * 64 * 256;
#pragma unroll
    for (int nt = 0; nt < 16; ++nt) {
      const int col = nt * 16 + m_l;
      const float bb = bias[col];
#pragma unroll
      for (int r = 0; r < 4; ++r)
        outb[(size_t)(w * 16 + quad * 4 + r) * 256 + col] = acc[nt][r] + bb;
    }
  }
}

// ---------------------------------------------------------------------------
extern "C" void kernel_launch(void* const* d_in, const int* in_sizes, int n_in,
                              void* d_out, int out_size, void* d_ws,
                              size_t ws_size, hipStream_t stream) {
  const float* q    = (const float*)d_in[0];
  const float* kv   = (const float*)d_in[1];
  const float* Wq   = (const float*)d_in[2];
  const float* Wk   = (const float*)d_in[3];
  const float* Wv   = (const float*)d_in[4];
  const float* Wout = (const float*)d_in[5];
  const float* bout = (const float*)d_in[6];

  unsigned short* ws      = (unsigned short*)d_ws;
  unsigned short* Afrag   = ws;            // 65536 shorts
  unsigned short* WVOfrag = ws + 65536;    // 65536 shorts

  hipLaunchKernelGGL(prep_kernel, dim3(512), dim3(256), 0, stream,
                     Wq, Wk, Wv, Wout, Afrag, WVOfrag);
  hipLaunchKernelGGL(fused_kernel, dim3(256), dim3(256), 0, stream,
                     q, kv, Afrag, WVOfrag, bout, (float*)d_out);
}